// Round 20
// baseline (67.145 us; speedup 1.0000x reference)
//
#include <hip/hip_runtime.h>
#include <hip/hip_bf16.h>

#define NN   4096
#define INF_ 256
#define OUTF 64
#define NH   8
#define HSTR 72
#define NPAD 576   // 8 heads * 72 (64 g + 1 e + 7 zero pad)

using bf16x8 = __attribute__((ext_vector_type(8))) short;
using f32x4  = __attribute__((ext_vector_type(4))) float;
using i32x2  = __attribute__((ext_vector_type(2))) int;
typedef unsigned long long ull;

#define SEP()      asm volatile("" ::: "memory")
#define WAITVM(N)  asm volatile("s_waitcnt vmcnt(" #N ")" ::: "memory")
#define WAITLGKM() asm volatile("s_waitcnt lgkmcnt(0)" ::: "memory")
#define BAR()      asm volatile("s_barrier" ::: "memory")
#define SCHEDBAR() __builtin_amdgcn_sched_barrier(0)

__device__ __forceinline__ void gload_lds16(const void* g, void* l) {
  __builtin_amdgcn_global_load_lds((__attribute__((address_space(1))) void*)(g),
                                   (__attribute__((address_space(3))) void*)(l),
                                   16, 0, 0);
}

// compiler-invisible 8B global load (round-10/11 validated pattern).
__device__ __forceinline__ i32x2 gload_i2(const void* p) {
  i32x2 r;
  asm volatile("global_load_dwordx2 %0, %1, off" : "=v"(r) : "v"(p));
  return r;
}

__device__ __forceinline__ unsigned short f2bf(float x) {
  unsigned u = __float_as_uint(x);
  unsigned r = (u + 0x7FFFu + ((u >> 16) & 1u)) >> 16;
  return (unsigned short)r;
}

// Interleaved-layout expand: n0 = 4 even-col bits, n1 = 4 odd-col bits.
__device__ __forceinline__ bf16x8 expand_nib(unsigned n0, unsigned n1) {
  union { uint4 u; bf16x8 v; } cv;
  cv.u.x = ( n0       & 1u) * 0x3F80u + ( n1       & 1u) * 0x3F800000u;
  cv.u.y = ((n0 >> 1) & 1u) * 0x3F80u + ((n1 >> 1) & 1u) * 0x3F800000u;
  cv.u.z = ((n0 >> 2) & 1u) * 0x3F80u + ((n1 >> 2) & 1u) * 0x3F800000u;
  cv.u.w = ((n0 >> 3) & 1u) * 0x3F80u + ((n1 >> 3) & 1u) * 0x3F800000u;
  return cv.v;
}

// ---------------- fused prologue: prep (blocks 0..255) + pack (256..2303) ----
// r19 version, byte-identical.
#define PREP_BLOCKS (NN / 16)                // 256
#define PACK_BLOCKS (NN / 2)                 // 2048 (2 rows per block)

__global__ __launch_bounds__(256) void k_pp(const int* __restrict__ adj,
                                            ull* __restrict__ Abits,
                                            const float* __restrict__ feat,
                                            const float* __restrict__ W,
                                            const float* __restrict__ att,
                                            unsigned short* __restrict__ Gt) {
  __shared__ alignas(16) unsigned char sm[32768];   // arena: pack 32 KB | prep ~21 KB
  int tid = threadIdx.x;

  if (blockIdx.x >= PREP_BLOCKS) {
    // ---- bit-pack via LDS staging.
    int blk = blockIdx.x - PREP_BLOCKS;             // 0..2047
    int r0  = blk * 2;
    int lane = tid & 63, wv = tid >> 6;
    const int* gsrc = adj + (size_t)r0 * NN + tid * 4;
#pragma unroll
    for (int rd = 0; rd < 8; ++rd)
      gload_lds16(gsrc + rd * 1024, sm + rd * 4096 + wv * 1024);
    WAITVM(0);
    __syncthreads();
    const int* srcL = (const int*)sm + (wv >> 1) * 4096 + (wv & 1) * 2048 + lane * 2;
    ull* dst = Abits + (size_t)(r0 + (wv >> 1)) * (NN / 64) + (wv & 1) * 32;
#pragma unroll
    for (int g = 0; g < 16; ++g) {
      i32x2 v = *(const i32x2*)(srcL + g * 128);
      ull m0 = __ballot(v[0] > 0);
      ull m1 = __ballot(v[1] > 0);
      if (lane == 0) {
        uint4 w;
        w.x = (unsigned)m0;         w.y = (unsigned)m1;
        w.z = (unsigned)(m0 >> 32); w.w = (unsigned)(m1 >> 32);
        *(uint4*)&dst[g * 2] = w;
      }
    }
    return;
  }

  // ---- prep: h = feat@W ; e = exp(h·a_dst) ; Gt build (16 rows/block)
  float (*fl)[INF_] = (float(*)[INF_])sm;                    // 16 KB
  float (*hl)[65]   = (float(*)[65])(sm + 16384);            // 4160 B
  float (*el)[16]   = (float(*)[16])(sm + 20544);            // 512 B
  int j0 = blockIdx.x * 16;
  const float4* src = (const float4*)(feat + (size_t)j0 * INF_);
  for (int i = tid; i < 16 * 64; i += 256) {
    int r = i >> 6, c4 = i & 63;
    *(float4*)&fl[r][c4 * 4] = src[i];
  }
  __syncthreads();
  int c  = tid & 63;
  int rg = tid >> 6;
  float acc[4] = {0.f, 0.f, 0.f, 0.f};
#pragma unroll 8
  for (int k = 0; k < INF_; ++k) {
    float w = W[k * OUTF + c];
#pragma unroll
    for (int m = 0; m < 4; ++m) acc[m] = fmaf(fl[rg * 4 + m][k], w, acc[m]);
  }
#pragma unroll
  for (int m = 0; m < 4; ++m) hl[rg * 4 + m][c] = acc[m];
  __syncthreads();
  if (tid < NH * 16) {
    int hh = tid >> 4, row = tid & 15;
    float d = 0.f;
#pragma unroll 8
    for (int f = 0; f < 64; ++f) d = fmaf(hl[row][f], att[hh * 128 + 64 + f], d);
    el[hh][row] = expf(d);
  }
  __syncthreads();
  for (int i = tid; i < NPAD * 8; i += 256) {
    int u = i & 7, cc = i >> 3;
    int j2 = u * 2;
    int hh2 = cc / HSTR, c2 = cc - hh2 * HSTR;
    float e0 = el[hh2][j2], e1 = el[hh2][j2 + 1];
    float v0, v1;
    if (c2 < 64)      { v0 = e0 * hl[j2][c2]; v1 = e1 * hl[j2 + 1][c2]; }
    else if (c2 == 64){ v0 = e0;              v1 = e1; }
    else              { v0 = 0.f;             v1 = 0.f; }
    ushort2 o; o.x = f2bf(v0); o.y = f2bf(v1);
    *(ushort2*)&Gt[(size_t)cc * NN + j0 + j2] = o;
  }
}

// ---- Cp[ks] = A(bit-packed 0/1, expanded in-reg) @ Gt^T ----
// Sync skeleton validated 8x. CHANGE vs r19: 2M x 2N wave grid (wave tile
// 64x48) instead of all-M — each wave reads 6 B-fragments/iter instead of 12,
// halving the dominant LDS-read traffic. A: 4 bit-loads/iter (rows
// wm*64 + {0,16,32,48} + r15). vmcnt queue: [B(kt)3][A(kt)4][B(kt+1)3] ->
// steady top-wait stays vmcnt(3); tail vmcnt(0).
#define BM 128
#define BN 96
#define BK 64
#define KS 4
#define NT 16                 // (NN/KS)/BK
#define NTILE 6               // 576/96
#define MTILE 32
#define BSZ (BN * BK)         // 6144 ushorts = 12 KB per B buffer

__global__ __launch_bounds__(256, 3) void k_gemm(const ull* __restrict__ Abits,
                                                 const unsigned short* __restrict__ Bsrc,
                                                 float* __restrict__ Cp) {
  __shared__ alignas(16) unsigned short Bs[3 * BSZ];     // 36 KB total LDS

  // bijective XCD swizzle: nwg = 768 (%8==0); nt fastest.
  int id  = blockIdx.x;
  int wg  = (id & 7) * (768 >> 3) + (id >> 3);
  int nt  = wg % NTILE;
  int mt  = (wg / NTILE) % MTILE;
  int ks  = wg / (NTILE * MTILE);

  int m0 = mt * BM, n0 = nt * BN, k0 = ks * (NT * BK);
  int tid = threadIdx.x;
  int lane = tid & 63, wid = tid >> 6;
  int wm = wid >> 1, wn = wid & 1;         // 2x2 waves: wave tile 64x48
  f32x4 acc[4][3] = {};

  int hi = lane >> 4, r15 = lane & 15, x7 = lane & 7;
  int p0 = hi * 4;

  // A-bit pointers: rows m0 + wm*64 + {0,16,32,48} + r15, one u64 per K-tile.
  const ull* A0 = Abits + (size_t)(m0 + wm * 64 + r15) * (NN / 64) + (k0 >> 6);
  const ull* A1 = A0 + (size_t)16 * (NN / 64);
  const ull* A2 = A0 + (size_t)32 * (NN / 64);
  const ull* A3 = A0 + (size_t)48 * (NN / 64);

  // B: global_load_lds with pre-swizzled source (3 chunks of 32 rows).
  int brow = tid >> 3, bgrp = tid & 7;
  const unsigned short* Bg = Bsrc + (size_t)(n0 + brow) * NN + k0
                           + (size_t)((bgrp ^ (brow & 7)) * 8);

  i32x2 ra[4];        // [m] — lo dword = even-col bits, hi dword = odd-col bits

#define ALOAD(KT)                                                             \
  do { ra[0] = gload_i2(A0 + (KT)); ra[1] = gload_i2(A1 + (KT));              \
       ra[2] = gload_i2(A2 + (KT)); ra[3] = gload_i2(A3 + (KT)); } while (0)

#define CONVERT()                                                             \
  do { _Pragma("unroll") for (int m = 0; m < 4; ++m) {                        \
    unsigned lo = (unsigned)ra[m][0], hb = (unsigned)ra[m][1];                \
    af[m][0] = expand_nib((lo >> p0) & 0xFu, (hb >> p0) & 0xFu);              \
    af[m][1] = expand_nib((lo >> (p0 + 16)) & 0xFu, (hb >> (p0 + 16)) & 0xFu);\
  } } while (0)

#define BSTAGE(BIO, KO)                                                       \
  do { _Pragma("unroll") for (int r = 0; r < 3; ++r)                          \
    gload_lds16(Bg + (size_t)(r * 32) * NN + (KO),                            \
                &Bs[(unsigned)(BIO) + (unsigned)((r * 32 + wid * 8) * BK)]);  \
  } while (0)

#define COMPUTE(BCO)                                                          \
  do { _Pragma("unroll") for (int kk = 0; kk < 2; ++kk) {                     \
    bf16x8 bfr[3];                                                            \
    _Pragma("unroll") for (int n = 0; n < 3; ++n)                             \
      bfr[n] = *(const bf16x8*)&Bs[(unsigned)(BCO) +                          \
                                   (unsigned)((wn * 48 + n * 16 + r15) * BK)  \
                                   + (unsigned)(((kk * 4 + hi) ^ x7) * 8)];   \
    _Pragma("unroll") for (int m = 0; m < 4; ++m)                             \
      _Pragma("unroll") for (int n = 0; n < 3; ++n)                           \
        acc[m][n] = __builtin_amdgcn_mfma_f32_16x16x32_bf16(af[m][kk], bfr[n],\
                                                            acc[m][n], 0,0,0);\
  } } while (0)

  bf16x8 af[4][2];

  // prologue: B(0)->buf0, A(0)->ra, B(1)->buf1   (queue: B0=3, A0=4, B1=3)
  BSTAGE(0, 0); SEP();
  ALOAD(0);     SEP();
  BSTAGE(BSZ, BK);

#pragma unroll
  for (int kt = 0; kt < NT; ++kt) {
    if (kt < NT - 1) { WAITVM(3); } else { WAITVM(0); }
    SCHEDBAR();                    // rule #18: pin CONVERT after the wait
    CONVERT();                     // ra -> af (VALU); ra dead after this
    SCHEDBAR();                    // pin next ALOAD below (no ra overlap)
    if (kt + 1 < NT) { ALOAD(kt + 1); SEP(); }
    WAITLGKM();                    // own ds_reads retired (race fix)
    BAR();                         // all waves done reading buf((kt+2)%3)
    if (kt + 2 < NT) BSTAGE((unsigned)(((kt + 2) % 3) * BSZ), (kt + 2) * BK);
    COMPUTE((unsigned)((kt % 3) * BSZ));
  }

  float* Cout = Cp + (size_t)ks * NN * NPAD;
#pragma unroll
  for (int m = 0; m < 4; ++m)
#pragma unroll
    for (int n = 0; n < 3; ++n)
#pragma unroll
      for (int j = 0; j < 4; ++j) {
        int row = m0 + wm * 64 + m * 16 + hi * 4 + j;
        int col = n0 + wn * 48 + n * 16 + r15;
        Cout[(size_t)row * NPAD + col] = acc[m][n][j];
      }
#undef ALOAD
#undef CONVERT
#undef BSTAGE
#undef COMPUTE
}

// ---------------- epilogue: out[i,f] = (1/8) sum_h num/den over KS partials ----------------
__global__ __launch_bounds__(256) void k_epi(const float* __restrict__ Cp,
                                             float* __restrict__ out) {
  int idx = blockIdx.x * 256 + threadIdx.x;
  int i = idx >> 6, f = idx & 63;
  const float* row = Cp + (size_t)i * NPAD;
  const size_t stride = (size_t)NN * NPAD;
  float s = 0.f;
#pragma unroll
  for (int hh = 0; hh < NH; ++hh) {
    float num = 0.f, den = 0.f;
#pragma unroll
    for (int ks = 0; ks < KS; ++ks) {
      num += row[ks * stride + hh * HSTR + f];
      den += row[ks * stride + hh * HSTR + 64];
    }
    float inv = (den > 0.f) ? (1.f / den) : 0.f;
    s = fmaf(num, inv, s);
  }
  out[idx] = 0.125f * s;
}

extern "C" void kernel_launch(void* const* d_in, const int* in_sizes, int n_in,
                              void* d_out, int out_size, void* d_ws, size_t ws_size,
                              hipStream_t stream) {
  const float* feat = (const float*)d_in[0];
  const int*   adj  = (const int*)d_in[1];
  const float* W    = (const float*)d_in[2];
  const float* att  = (const float*)d_in[3];
  float* out = (float*)d_out;

  const size_t GT_B = (size_t)NPAD * NN * 2;         // 4.5 MB
  const size_t AB_B = (size_t)NN * (NN / 64) * 8;    // 2 MB
  char* ws = (char*)d_ws;
  unsigned short* Gt    = (unsigned short*)(ws);
  ull*            Abits = (ull*)(ws + GT_B);
  float*          Cp    = (float*)(ws + GT_B + AB_B); // KS x 9.4 MB partials

  k_pp  <<<PREP_BLOCKS + PACK_BLOCKS, 256, 0, stream>>>(adj, Abits, feat, W, att, Gt);
  k_gemm<<<NTILE * MTILE * KS, 256, 0, stream>>>(Abits, Gt, Cp);
  k_epi <<<NN * OUTF / 256, 256, 0, stream>>>(Cp, out);
}

// Round 21
// 56.961 us; speedup vs baseline: 1.1788x; 1.1788x over previous
//
#include <hip/hip_runtime.h>
#include <hip/hip_bf16.h>

#define NN   4096
#define INF_ 256
#define OUTF 64
#define NH   8
#define HSTR 72
#define NPAD 576   // 8 heads * 72 (64 g + 1 e + 7 zero pad)

using bf16x8 = __attribute__((ext_vector_type(8))) short;
using f32x4  = __attribute__((ext_vector_type(4))) float;
using i32x2  = __attribute__((ext_vector_type(2))) int;
typedef unsigned long long ull;

#define SEP()      asm volatile("" ::: "memory")
#define WAITVM(N)  asm volatile("s_waitcnt vmcnt(" #N ")" ::: "memory")
#define WAITLGKM() asm volatile("s_waitcnt lgkmcnt(0)" ::: "memory")
#define BAR()      asm volatile("s_barrier" ::: "memory")
#define SCHEDBAR() __builtin_amdgcn_sched_barrier(0)

__device__ __forceinline__ void gload_lds16(const void* g, void* l) {
  __builtin_amdgcn_global_load_lds((__attribute__((address_space(1))) void*)(g),
                                   (__attribute__((address_space(3))) void*)(l),
                                   16, 0, 0);
}

// compiler-invisible 8B global load (round-10/11 validated pattern).
__device__ __forceinline__ i32x2 gload_i2(const void* p) {
  i32x2 r;
  asm volatile("global_load_dwordx2 %0, %1, off" : "=v"(r) : "v"(p));
  return r;
}

__device__ __forceinline__ unsigned short f2bf(float x) {
  unsigned u = __float_as_uint(x);
  unsigned r = (u + 0x7FFFu + ((u >> 16) & 1u)) >> 16;
  return (unsigned short)r;
}

// Interleaved-layout expand: n0 = 4 even-col bits, n1 = 4 odd-col bits.
__device__ __forceinline__ bf16x8 expand_nib(unsigned n0, unsigned n1) {
  union { uint4 u; bf16x8 v; } cv;
  cv.u.x = ( n0       & 1u) * 0x3F80u + ( n1       & 1u) * 0x3F800000u;
  cv.u.y = ((n0 >> 1) & 1u) * 0x3F80u + ((n1 >> 1) & 1u) * 0x3F800000u;
  cv.u.z = ((n0 >> 2) & 1u) * 0x3F80u + ((n1 >> 2) & 1u) * 0x3F800000u;
  cv.u.w = ((n0 >> 3) & 1u) * 0x3F80u + ((n1 >> 3) & 1u) * 0x3F800000u;
  return cv.v;
}

// ---------------- fused prologue: prep (blocks 0..255) + pack (256..2303) ----
// r19 best-validated version, byte-identical.
#define PREP_BLOCKS (NN / 16)                // 256
#define PACK_BLOCKS (NN / 2)                 // 2048 (2 rows per block)

__global__ __launch_bounds__(256) void k_pp(const int* __restrict__ adj,
                                            ull* __restrict__ Abits,
                                            const float* __restrict__ feat,
                                            const float* __restrict__ W,
                                            const float* __restrict__ att,
                                            unsigned short* __restrict__ Gt) {
  __shared__ alignas(16) unsigned char sm[32768];   // arena: pack 32 KB | prep ~21 KB
  int tid = threadIdx.x;

  if (blockIdx.x >= PREP_BLOCKS) {
    // ---- bit-pack via LDS staging.
    int blk = blockIdx.x - PREP_BLOCKS;             // 0..2047
    int r0  = blk * 2;
    int lane = tid & 63, wv = tid >> 6;
    const int* gsrc = adj + (size_t)r0 * NN + tid * 4;
#pragma unroll
    for (int rd = 0; rd < 8; ++rd)
      gload_lds16(gsrc + rd * 1024, sm + rd * 4096 + wv * 1024);
    WAITVM(0);
    __syncthreads();
    const int* srcL = (const int*)sm + (wv >> 1) * 4096 + (wv & 1) * 2048 + lane * 2;
    ull* dst = Abits + (size_t)(r0 + (wv >> 1)) * (NN / 64) + (wv & 1) * 32;
#pragma unroll
    for (int g = 0; g < 16; ++g) {
      i32x2 v = *(const i32x2*)(srcL + g * 128);
      ull m0 = __ballot(v[0] > 0);
      ull m1 = __ballot(v[1] > 0);
      if (lane == 0) {
        uint4 w;
        w.x = (unsigned)m0;         w.y = (unsigned)m1;
        w.z = (unsigned)(m0 >> 32); w.w = (unsigned)(m1 >> 32);
        *(uint4*)&dst[g * 2] = w;
      }
    }
    return;
  }

  // ---- prep: h = feat@W ; e = exp(h·a_dst) ; Gt build (16 rows/block)
  float (*fl)[INF_] = (float(*)[INF_])sm;                    // 16 KB
  float (*hl)[65]   = (float(*)[65])(sm + 16384);            // 4160 B
  float (*el)[16]   = (float(*)[16])(sm + 20544);            // 512 B
  int j0 = blockIdx.x * 16;
  const float4* src = (const float4*)(feat + (size_t)j0 * INF_);
  for (int i = tid; i < 16 * 64; i += 256) {
    int r = i >> 6, c4 = i & 63;
    *(float4*)&fl[r][c4 * 4] = src[i];
  }
  __syncthreads();
  int c  = tid & 63;
  int rg = tid >> 6;
  float acc[4] = {0.f, 0.f, 0.f, 0.f};
#pragma unroll 8
  for (int k = 0; k < INF_; ++k) {
    float w = W[k * OUTF + c];
#pragma unroll
    for (int m = 0; m < 4; ++m) acc[m] = fmaf(fl[rg * 4 + m][k], w, acc[m]);
  }
#pragma unroll
  for (int m = 0; m < 4; ++m) hl[rg * 4 + m][c] = acc[m];
  __syncthreads();
  if (tid < NH * 16) {
    int hh = tid >> 4, row = tid & 15;
    float d = 0.f;
#pragma unroll 8
    for (int f = 0; f < 64; ++f) d = fmaf(hl[row][f], att[hh * 128 + 64 + f], d);
    el[hh][row] = expf(d);
  }
  __syncthreads();
  for (int i = tid; i < NPAD * 8; i += 256) {
    int u = i & 7, cc = i >> 3;
    int j2 = u * 2;
    int hh2 = cc / HSTR, c2 = cc - hh2 * HSTR;
    float e0 = el[hh2][j2], e1 = el[hh2][j2 + 1];
    float v0, v1;
    if (c2 < 64)      { v0 = e0 * hl[j2][c2]; v1 = e1 * hl[j2 + 1][c2]; }
    else if (c2 == 64){ v0 = e0;              v1 = e1; }
    else              { v0 = 0.f;             v1 = 0.f; }
    ushort2 o; o.x = f2bf(v0); o.y = f2bf(v1);
    *(ushort2*)&Gt[(size_t)cc * NN + j0 + j2] = o;
  }
}

// ---- Cp[ks] = A(bit-packed 0/1, expanded in-reg) @ Gt^T ----
// r19 verbatim: all-M wave layout (r20's 2Mx2N regressed: doubled A-path
// redundancy + register pressure outweighed the saved B ds_reads).
#define BM 128
#define BN 96
#define BK 64
#define KS 4
#define NT 16                 // (NN/KS)/BK
#define NTILE 6               // 576/96
#define MTILE 32
#define BSZ (BN * BK)         // 6144 ushorts = 12 KB per B buffer

__global__ __launch_bounds__(256, 3) void k_gemm(const ull* __restrict__ Abits,
                                                 const unsigned short* __restrict__ Bsrc,
                                                 float* __restrict__ Cp) {
  __shared__ alignas(16) unsigned short Bs[3 * BSZ];     // 36 KB total LDS

  // bijective XCD swizzle: nwg = 768 (%8==0); nt fastest.
  int id  = blockIdx.x;
  int wg  = (id & 7) * (768 >> 3) + (id >> 3);
  int nt  = wg % NTILE;
  int mt  = (wg / NTILE) % MTILE;
  int ks  = wg / (NTILE * MTILE);

  int m0 = mt * BM, n0 = nt * BN, k0 = ks * (NT * BK);
  int tid = threadIdx.x;
  int lane = tid & 63, wid = tid >> 6;     // 4 waves, all-M: wave rows wid*32..+31
  f32x4 acc[2][6] = {};

  int hi = lane >> 4, r15 = lane & 15, x7 = lane & 7;
  int p0 = hi * 4;

  // A-bit pointers: one u64 per row per K-tile (interleaved even/odd dwords).
  const ull* A0 = Abits + (size_t)(m0 + wid * 32 + r15) * (NN / 64) + (k0 >> 6);
  const ull* A1 = A0 + (size_t)16 * (NN / 64);

  // B: global_load_lds with pre-swizzled source (3 chunks of 32 rows).
  int brow = tid >> 3, bgrp = tid & 7;
  const unsigned short* Bg = Bsrc + (size_t)(n0 + brow) * NN + k0
                           + (size_t)((bgrp ^ (brow & 7)) * 8);

  i32x2 ra[2];        // [m] — lo dword = even-col bits, hi dword = odd-col bits

#define ALOAD(KT)                                                             \
  do { ra[0] = gload_i2(A0 + (KT)); ra[1] = gload_i2(A1 + (KT)); } while (0)

#define CONVERT()                                                             \
  do { _Pragma("unroll") for (int m = 0; m < 2; ++m) {                        \
    unsigned lo = (unsigned)ra[m][0], hb = (unsigned)ra[m][1];                \
    af[m][0] = expand_nib((lo >> p0) & 0xFu, (hb >> p0) & 0xFu);              \
    af[m][1] = expand_nib((lo >> (p0 + 16)) & 0xFu, (hb >> (p0 + 16)) & 0xFu);\
  } } while (0)

#define BSTAGE(BIO, KO)                                                       \
  do { _Pragma("unroll") for (int r = 0; r < 3; ++r)                          \
    gload_lds16(Bg + (size_t)(r * 32) * NN + (KO),                            \
                &Bs[(unsigned)(BIO) + (unsigned)((r * 32 + wid * 8) * BK)]);  \
  } while (0)

#define COMPUTE(BCO)                                                          \
  do { _Pragma("unroll") for (int kk = 0; kk < 2; ++kk) {                     \
    bf16x8 bfr[6];                                                            \
    _Pragma("unroll") for (int n = 0; n < 6; ++n)                             \
      bfr[n] = *(const bf16x8*)&Bs[(unsigned)(BCO) +                          \
                                   (unsigned)((n * 16 + r15) * BK)            \
                                   + (unsigned)(((kk * 4 + hi) ^ x7) * 8)];   \
    _Pragma("unroll") for (int m = 0; m < 2; ++m)                             \
      _Pragma("unroll") for (int n = 0; n < 6; ++n)                           \
        acc[m][n] = __builtin_amdgcn_mfma_f32_16x16x32_bf16(af[m][kk], bfr[n],\
                                                            acc[m][n], 0,0,0);\
  } } while (0)

  bf16x8 af[2][2];

  // prologue: B(0)->buf0, A(0)->ra, B(1)->buf1   (queue: B0=3, A0=2, B1=3)
  BSTAGE(0, 0); SEP();
  ALOAD(0);     SEP();
  BSTAGE(BSZ, BK);

#pragma unroll
  for (int kt = 0; kt < NT; ++kt) {
    if (kt < NT - 1) { WAITVM(3); } else { WAITVM(0); }
    SCHEDBAR();                    // rule #18: pin CONVERT after the wait
    CONVERT();                     // ra -> af (VALU); ra dead after this
    SCHEDBAR();                    // pin next ALOAD below (no ra overlap)
    if (kt + 1 < NT) { ALOAD(kt + 1); SEP(); }
    WAITLGKM();                    // own ds_reads retired (race fix)
    BAR();                         // all waves done reading buf((kt+2)%3)
    if (kt + 2 < NT) BSTAGE((unsigned)(((kt + 2) % 3) * BSZ), (kt + 2) * BK);
    COMPUTE((unsigned)((kt % 3) * BSZ));
  }

  float* Cout = Cp + (size_t)ks * NN * NPAD;
#pragma unroll
  for (int m = 0; m < 2; ++m)
#pragma unroll
    for (int n = 0; n < 6; ++n)
#pragma unroll
      for (int j = 0; j < 4; ++j) {
        int row = m0 + wid * 32 + m * 16 + hi * 4 + j;
        int col = n0 + n * 16 + r15;
        Cout[(size_t)row * NPAD + col] = acc[m][n][j];
      }
#undef ALOAD
#undef CONVERT
#undef BSTAGE
#undef COMPUTE
}

// ---------------- epilogue: out[i,f] = (1/8) sum_h num/den over KS partials ----------------
__global__ __launch_bounds__(256) void k_epi(const float* __restrict__ Cp,
                                             float* __restrict__ out) {
  int idx = blockIdx.x * 256 + threadIdx.x;
  int i = idx >> 6, f = idx & 63;
  const float* row = Cp + (size_t)i * NPAD;
  const size_t stride = (size_t)NN * NPAD;
  float s = 0.f;
#pragma unroll
  for (int hh = 0; hh < NH; ++hh) {
    float num = 0.f, den = 0.f;
#pragma unroll
    for (int ks = 0; ks < KS; ++ks) {
      num += row[ks * stride + hh * HSTR + f];
      den += row[ks * stride + hh * HSTR + 64];
    }
    float inv = (den > 0.f) ? (1.f / den) : 0.f;
    s = fmaf(num, inv, s);
  }
  out[idx] = 0.125f * s;
}

extern "C" void kernel_launch(void* const* d_in, const int* in_sizes, int n_in,
                              void* d_out, int out_size, void* d_ws, size_t ws_size,
                              hipStream_t stream) {
  const float* feat = (const float*)d_in[0];
  const int*   adj  = (const int*)d_in[1];
  const float* W    = (const float*)d_in[2];
  const float* att  = (const float*)d_in[3];
  float* out = (float*)d_out;

  const size_t GT_B = (size_t)NPAD * NN * 2;         // 4.5 MB
  const size_t AB_B = (size_t)NN * (NN / 64) * 8;    // 2 MB
  char* ws = (char*)d_ws;
  unsigned short* Gt    = (unsigned short*)(ws);
  ull*            Abits = (ull*)(ws + GT_B);
  float*          Cp    = (float*)(ws + GT_B + AB_B); // KS x 9.4 MB partials

  k_pp  <<<PREP_BLOCKS + PACK_BLOCKS, 256, 0, stream>>>(adj, Abits, feat, W, att, Gt);
  k_gemm<<<NTILE * MTILE * KS, 256, 0, stream>>>(Abits, Gt, Cp);
  k_epi <<<NN * OUTF / 256, 256, 0, stream>>>(Cp, out);
}